// Round 11
// baseline (109.106 us; speedup 1.0000x reference)
//
#include <hip/hip_runtime.h>
#include <hip/hip_bf16.h>

typedef __bf16 bf16x8 __attribute__((ext_vector_type(8)));
typedef float  f32x4  __attribute__((ext_vector_type(4)));
typedef float  f32x16 __attribute__((ext_vector_type(16)));

#define NB 16
#define NC 32
#define NH 32
#define NW 2048
#define NK (NC*NH)   // 1024
#define LOG2E 1.4426950408889634f
#define TPAD 1040    // LDS row pitch (bf16 units): 2080 B, 16B-aligned

static __device__ __forceinline__ unsigned int pk2(float a, float b) {
    union { __bf16 h[2]; unsigned int u; } z;
    z.h[0] = (__bf16)a; z.h[1] = (__bf16)b;
    return z.u;
}

// ---------------------------------------------------------------------------
// Kernel 0: weights -> bf16. wb layout [3][32][1024].
// wq section is pre-scaled by log2e so attention can use native exp2.
// ---------------------------------------------------------------------------
__global__ __launch_bounds__(256) void wprep_kernel(
    const float* __restrict__ wq, const float* __restrict__ wk,
    const float* __restrict__ wv, __bf16* __restrict__ wb)
{
    const int i = blockIdx.x * 256 + threadIdx.x;        // 24576 float4 units
    const float* srcs[3] = { wq, wk, wv };
    float4 v = *(const float4*)(srcs[i >> 13] + (size_t)(i & 8191) * 4);
    const float sc = (i >> 13) == 0 ? LOG2E : 1.0f;
    union { __bf16 h[4]; unsigned long long u; } z;
    z.h[0] = (__bf16)(v.x * sc); z.h[1] = (__bf16)(v.y * sc);
    z.h[2] = (__bf16)(v.z * sc); z.h[3] = (__bf16)(v.w * sc);
    *(unsigned long long*)(wb + (size_t)i * 4) = z.u;
}

// ---------------------------------------------------------------------------
// Kernel 1 (v3): QKV projection with WHOLE-TILE staging.
// Stage the full 32w x 1024k x-tile to LDS first (32 float4 loads/thread,
// deep ILP, one barrier) -> the K-loop has NO global->compute latency chain:
// each wave computes its K-quarter from LDS (12 MFMA/step) + L2-resident wb.
// Combine (24 KB) aliases the dead tile behind a barrier. 66.5 KB LDS.
// ---------------------------------------------------------------------------
__global__ __launch_bounds__(256) void proj_kernel(
    const float* __restrict__ x, const __bf16* __restrict__ wb,
    const float* __restrict__ bq, const float* __restrict__ bk,
    const float* __restrict__ bv,
    __bf16* __restrict__ qT, __bf16* __restrict__ kT, __bf16* __restrict__ V)
{
    const int b    = blockIdx.x >> 6;
    const int wt   = blockIdx.x & 63;
    const int wave = threadIdx.x >> 6;       // = K quarter
    const int lane = threadIdx.x & 63;
    const int g    = lane >> 4;
    const int lr   = lane & 15;
    const int w0   = wt * 32;

    __shared__ __align__(16) char smem_raw[32 * TPAD * 2];   // 66560 B
    __bf16 (*tile)[TPAD] = reinterpret_cast<__bf16(*)[TPAD]>(smem_raw);
    f32x4 (*part)[6][64] = reinterpret_cast<f32x4(*)[6][64]>(smem_raw);

    const float* xb = x + (size_t)b * NK * NW;

    // ---- stage the whole tile: thread -> w=(t&7)*4..+3, k=(t>>3)+32*pass ----
    {
        const int swq = threadIdx.x & 7;
        const int skr = threadIdx.x >> 3;    // 0..31
        const float* xs = xb + w0 + swq * 4;
        __bf16* wp0 = &tile[swq * 4][skr];
        #pragma unroll 8
        for (int pass = 0; pass < 32; ++pass) {
            const int k = pass * 32 + skr;
            const float4 v = *(const float4*)(xs + (size_t)k * NW);
            __bf16* wp = wp0 + pass * 32;
            wp[0*TPAD] = (__bf16)v.x;
            wp[1*TPAD] = (__bf16)v.y;
            wp[2*TPAD] = (__bf16)v.z;
            wp[3*TPAD] = (__bf16)v.w;
        }
    }
    __syncthreads();

    // ---- K-quarter compute, all A-frags from LDS ----
    const int k0 = wave * 256;
    f32x4 acc[2][6];
    #pragma unroll
    for (int mt = 0; mt < 2; ++mt)
        #pragma unroll
        for (int nt = 0; nt < 6; ++nt)
            acc[mt][nt] = f32x4{0.f, 0.f, 0.f, 0.f};

    #pragma unroll
    for (int s = 0; s < 8; ++s) {
        const int kk = k0 + s * 32;
        const bf16x8 af0 = *(const bf16x8*)&tile[lr][kk + g*8];
        const bf16x8 af1 = *(const bf16x8*)&tile[16 + lr][kk + g*8];
        bf16x8 bfv[6];
        #pragma unroll
        for (int nt = 0; nt < 6; ++nt)
            bfv[nt] = *(const bf16x8*)(wb + (size_t)(nt >> 1) * 32768
                                          + (size_t)((nt & 1) * 16 + lr) * NK
                                          + kk + g*8);
        #pragma unroll
        for (int nt = 0; nt < 6; ++nt) {
            acc[0][nt] = __builtin_amdgcn_mfma_f32_16x16x32_bf16(
                af0, bfv[nt], acc[0][nt], 0, 0, 0);
            acc[1][nt] = __builtin_amdgcn_mfma_f32_16x16x32_bf16(
                af1, bfv[nt], acc[1][nt], 0, 0, 0);
        }
    }

    // ---- combine the 4 K-quarters (part aliases tile, barrier-guarded) ----
    const float* biases[3] = { bq, bk, bv };
    #pragma unroll
    for (int mt = 0; mt < 2; ++mt) {
        __syncthreads();                 // tile dead / prev part round done
        #pragma unroll
        for (int nt = 0; nt < 6; ++nt)
            part[wave][nt][lane] = acc[mt][nt];
        __syncthreads();
        #pragma unroll
        for (int q = 0; q < 2; ++q) {
            const int nt = wave + q * 4;
            if (nt < 6) {
                f32x4 s = part[0][nt][lane];
                #pragma unroll
                for (int sl = 1; sl < 4; ++sl) s += part[sl][nt][lane];
                const int pid = nt >> 1;             // 0=q,1=k,2=v
                const int o   = (nt & 1) * 16 + lr;
                float bb = biases[pid][o];
                if (pid == 0) bb *= LOG2E;
                if (pid < 2) {
                    __bf16* dst = (pid ? kT : qT) + (size_t)b * NW * NC;
                    #pragma unroll
                    for (int r = 0; r < 4; ++r) {
                        const int w = w0 + mt*16 + g*4 + r;
                        dst[(size_t)w * NC + o] = (__bf16)(s[r] + bb);
                    }
                } else {
                    union { __bf16 h[4]; unsigned long long u; } z;
                    #pragma unroll
                    for (int r = 0; r < 4; ++r) z.h[r] = (__bf16)(s[r] + bb);
                    __bf16* dst = V + ((size_t)b * NC + o) * NW + (w0 + mt*16 + g*4);
                    *(unsigned long long*)dst = z.u;
                }
            }
        }
    }
}

// ---------------------------------------------------------------------------
// Kernel 2: flash attention (R10, unchanged): fixed-max softmax, sigma-
// permuted K rows (lane-local PV fragments), software-pipelined loop,
// exp2 via __builtin_amdgcn_exp2f, NT out stores.
// ---------------------------------------------------------------------------
__global__ __launch_bounds__(256) void attn_kernel(
    const float* __restrict__ x,
    const __bf16* __restrict__ qT, const __bf16* __restrict__ kT,
    const __bf16* __restrict__ V,
    float* __restrict__ out)
{
    const int b    = blockIdx.x >> 6;
    const int wt   = blockIdx.x & 63;
    const int w0   = wt * 32;
    const int wave = threadIdx.x >> 6;        // KV slice 0..3
    const int lane = threadIdx.x & 63;
    const int wl = lane & 31, hi = lane >> 5;
    const int swl = (wl & 0x13) | ((wl & 4) << 1) | ((wl & 8) >> 1);

    const __bf16* qTb = qT + (size_t)b * NW * NC;
    const __bf16* kTb = kT + (size_t)b * NW * NC;
    const __bf16* Vb  = V  + (size_t)b * NC * NW;

    const __bf16* qrow = qTb + (size_t)(w0 + wl) * NC;
    const bf16x8 qf0 = *(const bf16x8*)(qrow + hi*8);
    const bf16x8 qf1 = *(const bf16x8*)(qrow + 16 + hi*8);

    f32x16 acc, z16;
    #pragma unroll
    for (int r = 0; r < 16; ++r) { acc[r] = 0.f; z16[r] = 0.f; }
    float lsum = 0.f;

    const int vbeg = wave * 512;
    const __bf16* kbase = kTb + (size_t)swl * NC;
    const __bf16* vbase = Vb + (size_t)wl * NW;

#define KLD0(V0) (*(const bf16x8*)(kbase + (size_t)(V0) * NC + hi*8))
#define KLD1(V0) (*(const bf16x8*)(kbase + (size_t)(V0) * NC + 16 + hi*8))
#define VLD0(V0) (*(const bf16x8*)(vbase + (V0) + hi*8))
#define VLD1(V0) (*(const bf16x8*)(vbase + (V0) + 16 + hi*8))

    bf16x8 k0r = KLD0(vbeg), k1r = KLD1(vbeg);
    f32x16 s_cur = __builtin_amdgcn_mfma_f32_32x32x16_bf16(k0r, qf0, z16, 0, 0, 0);
    s_cur = __builtin_amdgcn_mfma_f32_32x32x16_bf16(k1r, qf1, s_cur, 0, 0, 0);
    k0r = KLD0(vbeg + 32); k1r = KLD1(vbeg + 32);
    bf16x8 v0r = VLD0(vbeg), v1r = VLD1(vbeg);

    #pragma unroll
    for (int it = 0; it < 16; ++it) {
        f32x16 s_next;
        if (it < 15) {
            s_next = __builtin_amdgcn_mfma_f32_32x32x16_bf16(k0r, qf0, z16, 0, 0, 0);
            s_next = __builtin_amdgcn_mfma_f32_32x32x16_bf16(k1r, qf1, s_next, 0, 0, 0);
        }
        if (it < 14) {
            const int vn = vbeg + (it + 2) * 32;
            k0r = KLD0(vn); k1r = KLD1(vn);
        }

        float p[16];
        #pragma unroll
        for (int r = 0; r < 16; ++r) p[r] = __builtin_amdgcn_exp2f(s_cur[r]);
        float ts[8];
        #pragma unroll
        for (int r = 0; r < 8; ++r) ts[r] = p[r] + p[r+8];
        #pragma unroll
        for (int r = 0; r < 4; ++r) ts[r] += ts[r+4];
        lsum += (ts[0] + ts[1]) + (ts[2] + ts[3]);

        union { unsigned int u[4]; bf16x8 v; } pfa, pfb;
        #pragma unroll
        for (int i = 0; i < 4; ++i) pfa.u[i] = pk2(p[2*i],     p[2*i + 1]);
        #pragma unroll
        for (int i = 0; i < 4; ++i) pfb.u[i] = pk2(p[8 + 2*i], p[8 + 2*i + 1]);

        acc = __builtin_amdgcn_mfma_f32_32x32x16_bf16(v0r, pfa.v, acc, 0, 0, 0);
        acc = __builtin_amdgcn_mfma_f32_32x32x16_bf16(v1r, pfb.v, acc, 0, 0, 0);

        if (it < 15) {
            const int vn = vbeg + (it + 1) * 32;
            v0r = VLD0(vn); v1r = VLD1(vn);
            s_cur = s_next;
        }
    }
#undef KLD0
#undef KLD1
#undef VLD0
#undef VLD1
    lsum += __shfl_xor(lsum, 32);

    __shared__ float sl[4][32];
    __shared__ float sO[4][32][33];
    __shared__ float Of[32][33];

    if (hi == 0) sl[wave][wl] = lsum;
    #pragma unroll
    for (int r = 0; r < 16; ++r) {
        const int c = (r & 3) + 8*(r >> 2) + 4*hi;
        sO[wave][c][wl] = acc[r];
    }
    __syncthreads();

    {
        const int w  = threadIdx.x & 31;
        const int cg = threadIdx.x >> 5;
        const float L = (sl[0][w] + sl[1][w]) + (sl[2][w] + sl[3][w]);
        const float rL = 1.0f / L;
        #pragma unroll
        for (int cc = 0; cc < 4; ++cc) {
            const int c = cg * 4 + cc;
            const float o = ((sO[0][c][w] + sO[1][c][w]) +
                             (sO[2][c][w] + sO[3][c][w]));
            Of[c][w] = o * rL;
        }
    }
    __syncthreads();

    const float* xb = x   + (size_t)b * NC * NH * NW + w0;
    float*       ob = out + (size_t)b * NC * NH * NW + w0;
    const int chunk = threadIdx.x & 7;
    #pragma unroll
    for (int it = 0; it < 32; ++it) {
        const int row = it*32 + (threadIdx.x >> 3);
        const int c = row >> 5, h = row & 31;
        const size_t off = ((size_t)c * NH + h) * NW + chunk*4;
        const f32x4 xv = *(const f32x4*)(xb + off);
        f32x4 ov;
        ov[0] = Of[c][chunk*4 + 0] + xv[0];
        ov[1] = Of[c][chunk*4 + 1] + xv[1];
        ov[2] = Of[c][chunk*4 + 2] + xv[2];
        ov[3] = Of[c][chunk*4 + 3] + xv[3];
        __builtin_nontemporal_store(ov, (f32x4*)(ob + off));
    }
}

extern "C" void kernel_launch(void* const* d_in, const int* in_sizes, int n_in,
                              void* d_out, int out_size, void* d_ws, size_t ws_size,
                              hipStream_t stream)
{
    const float* x  = (const float*)d_in[0];
    const float* wq = (const float*)d_in[1];
    const float* bq = (const float*)d_in[2];
    const float* wk = (const float*)d_in[3];
    const float* bk = (const float*)d_in[4];
    const float* wv = (const float*)d_in[5];
    const float* bv = (const float*)d_in[6];
    float* out = (float*)d_out;

    // ws layout (bf16): qT [B][W][32] @0, kT @2MB, V [B][32][W] @4MB, wb @6MB
    char* ws = (char*)d_ws;
    __bf16* qT = (__bf16*)(ws);
    __bf16* kT = (__bf16*)(ws + (2u << 20));
    __bf16* V  = (__bf16*)(ws + (4u << 20));
    __bf16* wb = (__bf16*)(ws + (6u << 20));

    hipLaunchKernelGGL(wprep_kernel, dim3(96), dim3(256), 0, stream, wq, wk, wv, wb);
    hipLaunchKernelGGL(proj_kernel, dim3(NB * 64), dim3(256), 0, stream,
                       x, wb, bq, bk, bv, qT, kT, V);
    hipLaunchKernelGGL(attn_kernel, dim3(NB * 64), dim3(256), 0, stream,
                       x, qT, kT, V, out);
}